// Round 9
// baseline (28497.736 us; speedup 1.0000x reference)
//
#include <hip/hip_runtime.h>

// ---------------------------------------------------------------------------
// RITS recurrent scan, model-parallel persistent kernel, v5: ONE barrier/step.
// 8 groups x 64 batch rows; group = 32 blocks (1/CU), g = bid>>5, r = bid&31.
// Block r owns H-slice [16r,16r+16) for the LSTM gates/state. The ENTIRE
// F-chain (gamma_x, x_h, x_c, z_h, alpha, c_h, c_c) is computed FULLY LOCALLY
// by every block for its group's 64 rows -- the only cross-block exchange is
// h_dec (proven sc1 LLC protocol + flag barrier). 3 barriers/step -> 1.
//
// F-side weights are streamed as B-frags from global (read-only, L2-cached,
// shared by all blocks): W_hr 128KB, W_dx/W_fr 32KB, W_wc 64KB. Gates (96KB)
// in LDS. C-layout -> A-frag conversions between chained GEMMs use a private
// per-wave LDS transpose (no syncthreads; same-wave lgkmcnt fence).
// gamma_h(t+1) is computed from prefetched deltas(t+1) so P-final publishes
// h_dec(t+1) = h_new * gamma_h(t+1) directly (v3.2 technique).
//
// One-barrier WAR safety: consumer h_dec loads are drained by the vmcnt(0) at
// barrier entry (vmcnt counts loads), so a writer that passed barrier t can
// safely overwrite parity buffer (t+1)&1 at end of step t.
// 4 waves/block; wave w owns rows [g*64+w*16, +16) end-to-end.
// ---------------------------------------------------------------------------

using short8 = __attribute__((ext_vector_type(8))) short;
using f32x4  = __attribute__((ext_vector_type(4))) float;
using fvec4  = __attribute__((ext_vector_type(4))) float;
using ivec4  = __attribute__((ext_vector_type(4))) int;
using uvec4  = __attribute__((ext_vector_type(4))) unsigned int;

#define LOG2E 1.4426950408889634f

union U8 {
  unsigned u[4];
  unsigned long long q[2];
  short8 s;
  uvec4 v;
};

static __device__ __forceinline__ unsigned short f2bf(float f){
  unsigned u = __builtin_bit_cast(unsigned, f);
  u += 0x7fffu + ((u>>16)&1u);
  return (unsigned short)(u>>16);
}
static __device__ __forceinline__ float fexp2(float x){ return __builtin_amdgcn_exp2f(x); }
static __device__ __forceinline__ float frcp(float x){ return __builtin_amdgcn_rcpf(x); }
static __device__ __forceinline__ float sigm(float x){ return frcp(1.f + fexp2(-LOG2E*x)); }
static __device__ __forceinline__ float tanh_(float x){
  x = fminf(fmaxf(x,-10.f),10.f);
  float e = fexp2(2.f*LOG2E*x);
  return (e-1.f)*frcp(e+1.f);
}
static __device__ __forceinline__ f32x4 mfma16(short8 a, short8 b, f32x4 c){
  return __builtin_amdgcn_mfma_f32_16x16x32_bf16(a,b,c,0,0,0);
}
static __device__ __forceinline__ short8 frag_of(uvec4 v){ return __builtin_bit_cast(short8, v); }

// 16B frag load from exchange buffer (agent-scope relaxed -> sc1, reads LLC).
// PROVEN coherent (R1/R2/R4/R8); compiler tracks vmcnt for these loads.
static __device__ __forceinline__ short8 ex_frag(const unsigned short* p){
  const unsigned long long* q = (const unsigned long long*)p;
  U8 u;
  u.q[0] = __hip_atomic_load(q,     __ATOMIC_RELAXED, __HIP_MEMORY_SCOPE_AGENT);
  u.q[1] = __hip_atomic_load(q + 1, __ATOMIC_RELAXED, __HIP_MEMORY_SCOPE_AGENT);
  return u.s;
}

// u16 store with agent-scope coherence (write-through to LLC). PROVEN.
static __device__ __forceinline__ void st16_sc1(unsigned short* p, unsigned short v){
  unsigned vv = v;
  asm volatile("global_store_short %0, %1, off sc1" :: "v"(p), "v"(vv) : "memory");
}

// scatter one bf16 value at (row-in-tile rl, k-dim kk) into a 16x16x32
// A-frag-major exchange region with KF k-frags, m-tile mt. (proven layout)
static __device__ __forceinline__ void scatter_ex(unsigned short* exbuf, int mt, int KF,
                                                  int rl, int kk, float val){
  int kf = kk>>5, ko = kk&31;
  int L = rl + 16*(ko>>3);
  long off = ((long)(mt*KF+kf)*64 + L)*8 + (ko&7);
  st16_sc1(exbuf + off, f2bf(val));
}

// mask A-frag from two ivec4 register values (mask values exactly 0/1).
static __device__ __forceinline__ short8 mi_frag(ivec4 a, ivec4 b){
  U8 t;
  t.u[0] = (a.x?0x3F80u:0u) | ((a.y?0x3F80u:0u)<<16);
  t.u[1] = (a.z?0x3F80u:0u) | ((a.w?0x3F80u:0u)<<16);
  t.u[2] = (b.x?0x3F80u:0u) | ((b.y?0x3F80u:0u)<<16);
  t.u[3] = (b.z?0x3F80u:0u) | ((b.w?0x3F80u:0u)<<16);
  return t.s;
}

// Group barrier, flag-based, fence-free (PROVEN R2/R4/R8).
static __device__ __forceinline__ void group_barrier(unsigned* flags, int r,
                                                     int w, int lane, unsigned seq){
  asm volatile("s_waitcnt vmcnt(0)" ::: "memory");
  __syncthreads();
  if (threadIdx.x == 0)
    __hip_atomic_store(flags + r, seq, __ATOMIC_RELAXED, __HIP_MEMORY_SCOPE_AGENT);
  if (w == 0){
    for (;;){
      unsigned v = __hip_atomic_load(flags + (lane & 31), __ATOMIC_RELAXED,
                                     __HIP_MEMORY_SCOPE_AGENT);
      if (__all(v >= seq)) break;
      __builtin_amdgcn_s_sleep(1);
    }
  }
  __syncthreads();
}

// ---------------------------------------------------------------------------
// Weight packing (unchanged; blobs already contain the FULL matrices).
// B-frag: frag (tile,kf) holds B[n=tile*16+(lane&15)][k=kf*32+(lane>>4)*8+j].
// ---------------------------------------------------------------------------
__global__ void pack_generic(const float* __restrict__ src, uvec4* __restrict__ dst,
                             int KF, int srcK, int total){
  int t = blockIdx.x*256 + threadIdx.x;
  if (t >= total) return;
  int lane = t & 63, frag = t >> 6;
  int kf = frag % KF, tile = frag / KF;
  int n  = tile*16 + (lane & 15);
  int k0 = kf*32 + ((lane>>4)<<3);
  const float* s = src + (long)n*srcK + k0;
  U8 o;
  o.u[0] = (unsigned)f2bf(s[0]) | ((unsigned)f2bf(s[1])<<16);
  o.u[1] = (unsigned)f2bf(s[2]) | ((unsigned)f2bf(s[3])<<16);
  o.u[2] = (unsigned)f2bf(s[4]) | ((unsigned)f2bf(s[5])<<16);
  o.u[3] = (unsigned)f2bf(s[6]) | ((unsigned)f2bf(s[7])<<16);
  dst[t] = o.v;
}

// Gates blob: per role r, 4 n-tiles x 24 k-frags; n-tile = GATE, col = h_local
// (R = nt*512 + r*16 + n). K order: [c_c 0..127, m 128..255, h_dec 0..511].
__global__ void pack_gates(const float* __restrict__ Wih, const float* __restrict__ Whh,
                           uvec4* __restrict__ dst){
  int t = blockIdx.x*256 + threadIdx.x;
  if (t >= 3072*64) return;
  int lane = t & 63, frag = t >> 6;
  int kf = frag % 24; int rnt = frag / 24;
  int nt = rnt & 3; int r = rnt >> 2;
  int Rrow = nt*512 + r*16 + (lane & 15);
  int k = kf*32 + ((lane>>4)<<3);
  const float* s = (kf < 8) ? (Wih + (long)Rrow*256 + k)
                            : (Whh + (long)Rrow*512 + (k - 256));
  U8 o;
  o.u[0] = (unsigned)f2bf(s[0]) | ((unsigned)f2bf(s[1])<<16);
  o.u[1] = (unsigned)f2bf(s[2]) | ((unsigned)f2bf(s[3])<<16);
  o.u[2] = (unsigned)f2bf(s[4]) | ((unsigned)f2bf(s[5])<<16);
  o.u[3] = (unsigned)f2bf(s[6]) | ((unsigned)f2bf(s[7])<<16);
  dst[t] = o.v;
}

// ---------------------------------------------------------------------------
__global__ __launch_bounds__(256,1) void rits_main(
  const float* __restrict__ values, const int* __restrict__ masks, const float* __restrict__ deltas,
  const float* __restrict__ b_dh, const float* __restrict__ b_dx, const float* __restrict__ b_hr,
  const float* __restrict__ b_fr, const float* __restrict__ b_wc,
  const float* __restrict__ b_ih, const float* __restrict__ b_hh,
  const uvec4* __restrict__ BG, const uvec4* __restrict__ BDH, const uvec4* __restrict__ BHR,
  const uvec4* __restrict__ BDX, const uvec4* __restrict__ BFR, const uvec4* __restrict__ BWC,
  unsigned short* __restrict__ EX, unsigned* __restrict__ BAR,
  float* __restrict__ out)
{
  __shared__ __align__(16) uvec4 sh_g[96*64];            // 96KB gates B-frags
  __shared__ __align__(16) unsigned short sh_tr[4*2176]; // 17KB per-wave transpose
                                                         // total ~113KB, 1 block/CU

  const int tid = threadIdx.x;
  const int w = tid>>6, lane = tid&63, quad = lane>>4, ln = lane&15;
  const int g = blockIdx.x >> 5, r = blockIdx.x & 31;

  for (int idx = tid; idx < 96*64; idx += 256) sh_g[idx] = BG[(long)r*6144 + idx];

  // W_dh own H-slice B-frags (4 KB -> VGPRs)
  uvec4 pB[4];
  #pragma unroll
  for (int kf=0; kf<4; ++kf) pB[kf] = BDH[(r*4+kf)*64+lane];

  const float bias_dh = b_dh[r*16+ln];
  float bdx8[8], bhr8[8], bfr8[8], bwc8[8];
  #pragma unroll
  for (int nt=0; nt<8; ++nt){
    bdx8[nt] = b_dx[nt*16+ln];
    bhr8[nt] = b_hr[nt*16+ln];
    bfr8[nt] = b_fr[nt*16+ln];
    bwc8[nt] = b_wc[nt*16+ln];
  }
  float gbias[4];
  #pragma unroll
  for (int nt=0; nt<4; ++nt){
    int Rr = nt*512 + r*16 + ln;
    gbias[nt] = b_ih[Rr] + b_hh[Rr];
  }

  float hs[4] = {0,0,0,0}, cs[4] = {0,0,0,0};

  unsigned* flags = BAR + g*128;                          // 512B group stride
  unsigned seq = 0;

  unsigned short* const exb0 = EX + (long)g*32768;        // h_dec parity 0 (64KB)
  unsigned short* const exb1 = EX + (long)(8+g)*32768;    // h_dec parity 1

  const long rowA = (long)(g*64 + w*16 + ln);             // A-frag row (m=ln)
  const int scb = w*2176;                                 // per-wave scratch (u16)

  // ---- prologue: deltas(0) -> regs; publish h_dec(0)=0
  fvec4 dpre[8];
  {
    const long ib0 = rowA*256*128;
    #pragma unroll
    for (int kf=0; kf<4; ++kf){
      int c0 = kf*32 + quad*8;
      dpre[2*kf]   = *(const fvec4*)(deltas + ib0 + c0);
      dpre[2*kf+1] = *(const fvec4*)(deltas + ib0 + c0 + 4);
    }
  }
  __syncthreads();
  #pragma unroll
  for (int i=0;i<4;++i)
    scatter_ex(exb0, w, 16, quad*4+i, r*16+ln, 0.f);

  for (int t=0; t<256; ++t){
    unsigned short* const exh    = (t & 1) ? exb1 : exb0;
    unsigned short* const exh_nx = (t & 1) ? exb0 : exb1;
    const long ibase = (rowA*256 + t)*128;

    // ---- barrier: h_dec(t) visible (also drains our publishes/loads)
    group_barrier(flags, r, w, lane, ++seq);

    // ---- pack dA = deltas(t) A-frags from last iteration's prefetch
    short8 dA[4];
    #pragma unroll
    for (int kf=0; kf<4; ++kf){
      fvec4 lo = dpre[2*kf], hi = dpre[2*kf+1];
      U8 p8;
      p8.u[0] = (unsigned)f2bf(lo.x) | ((unsigned)f2bf(lo.y)<<16);
      p8.u[1] = (unsigned)f2bf(lo.z) | ((unsigned)f2bf(lo.w)<<16);
      p8.u[2] = (unsigned)f2bf(hi.x) | ((unsigned)f2bf(hi.y)<<16);
      p8.u[3] = (unsigned)f2bf(hi.z) | ((unsigned)f2bf(hi.w)<<16);
      dA[kf] = p8.s;
    }
    // ---- prefetch deltas(t+1)
    {
      const long ibn = (rowA*256 + ((t+1)&255))*128;
      #pragma unroll
      for (int kf=0; kf<4; ++kf){
        int c0 = kf*32 + quad*8;
        dpre[2*kf]   = *(const fvec4*)(deltas + ibn + c0);
        dpre[2*kf+1] = *(const fvec4*)(deltas + ibn + c0 + 4);
      }
    }
    // ---- mask A-frags (step t)
    short8 mA[4];
    #pragma unroll
    for (int kf=0; kf<4; ++kf){
      int c0 = kf*32 + quad*8;
      ivec4 a = *(const ivec4*)(masks + ibase + c0);
      ivec4 b = *(const ivec4*)(masks + ibase + c0 + 4);
      mA[kf] = mi_frag(a, b);
    }
    // ---- issue the 16 h_dec frag loads early (consumed by x_h below)
    short8 hA[16];
    #pragma unroll
    for (int kf=0; kf<16; ++kf)
      hA[kf] = ex_frag(exh + ((long)(w*16+kf)*64 + lane)*8);

    // ================= gamma_x FULL (local): deltas @ W_dx^T, 32 MFMAs
    {
      f32x4 gx;
      #pragma unroll
      for (int nt=0; nt<8; ++nt){
        gx[0]=0.f; gx[1]=0.f; gx[2]=0.f; gx[3]=0.f;
        #pragma unroll
        for (int kf=0; kf<4; ++kf)
          gx = mfma16(dA[kf], frag_of(BDX[(nt*4+kf)*64+lane]), gx);
        #pragma unroll
        for (int i=0;i<4;++i){
          float v = fexp2(-LOG2E * fmaxf(gx[i]+bdx8[nt], 0.f));
          sh_tr[scb + (quad*4+i)*136 + nt*16 + ln] = f2bf(v);
        }
      }
    }
    asm volatile("s_waitcnt lgkmcnt(0)" ::: "memory");
    __builtin_amdgcn_sched_barrier(0);
    short8 gxA[4];
    #pragma unroll
    for (int kf=0; kf<4; ++kf){
      U8 u; u.v = *(const uvec4*)&sh_tr[scb + ln*136 + kf*32 + quad*8];
      gxA[kf] = u.s;
    }
    __builtin_amdgcn_sched_barrier(0);

    // ================= x_h FULL (local): h_dec @ W_hr^T, 128 MFMAs (streamed)
    f32x4 xh[8];
    #pragma unroll
    for (int nt=0; nt<8; ++nt){
      f32x4 acc; acc[0]=0.f; acc[1]=0.f; acc[2]=0.f; acc[3]=0.f;
      #pragma unroll
      for (int kf=0; kf<16; ++kf)
        acc = mfma16(hA[kf], frag_of(BHR[(nt*16+kf)*64+lane]), acc);
      #pragma unroll
      for (int i=0;i<4;++i) acc[i] += bhr8[nt];
      xh[nt] = acc;
    }

    // ================= x_c FULL (local, C-layout) -> transpose -> xcA
    #pragma unroll
    for (int nt=0; nt<8; ++nt){
      #pragma unroll
      for (int i=0;i<4;++i){
        long io = ((long)(g*64 + w*16 + quad*4 + i)*256 + t)*128 + nt*16 + ln;
        int   m = masks[io];
        float v = values[io];
        float xc = m ? v : xh[nt][i];
        sh_tr[scb + (quad*4+i)*136 + nt*16 + ln] = f2bf(xc);
      }
    }
    asm volatile("s_waitcnt lgkmcnt(0)" ::: "memory");
    __builtin_amdgcn_sched_barrier(0);
    short8 xcA[4];
    #pragma unroll
    for (int kf=0; kf<4; ++kf){
      U8 u; u.v = *(const uvec4*)&sh_tr[scb + ln*136 + kf*32 + quad*8];
      xcA[kf] = u.s;
    }
    __builtin_amdgcn_sched_barrier(0);

    // ================= z_h & alpha FULL (local), 32 + 64 MFMAs (streamed)
    f32x4 zh[8], al[8];
    #pragma unroll
    for (int nt=0; nt<8; ++nt){
      f32x4 az; az[0]=0.f; az[1]=0.f; az[2]=0.f; az[3]=0.f;
      #pragma unroll
      for (int kf=0; kf<4; ++kf)
        az = mfma16(xcA[kf], frag_of(BFR[(nt*4+kf)*64+lane]), az);
      zh[nt] = az;
      f32x4 aa; aa[0]=0.f; aa[1]=0.f; aa[2]=0.f; aa[3]=0.f;
      #pragma unroll
      for (int kf=0; kf<4; ++kf)
        aa = mfma16(gxA[kf], frag_of(BWC[(nt*8+kf)*64+lane]), aa);
      #pragma unroll
      for (int kf=0; kf<4; ++kf)
        aa = mfma16(mA[kf], frag_of(BWC[(nt*8+4+kf)*64+lane]), aa);
      al[nt] = aa;
    }

    // ================= c_h / c_c FULL (local) + out store + transpose -> ccA
    #pragma unroll
    for (int nt=0; nt<8; ++nt){
      #pragma unroll
      for (int i=0;i<4;++i){
        long io = ((long)(g*64 + w*16 + quad*4 + i)*256 + t)*128 + nt*16 + ln;
        int   m = masks[io];
        float v = values[io];
        float zhv = zh[nt][i] + bfr8[nt];
        float alv = al[nt][i] + bwc8[nt];
        float ch  = alv*zhv + (1.f-alv)*xh[nt][i];
        float cc  = m ? v : ch;
        if (r == nt) out[io] = cc;            // blocks 0..7 store disjoint tiles
        sh_tr[scb + (quad*4+i)*136 + nt*16 + ln] = f2bf(cc);
      }
    }
    asm volatile("s_waitcnt lgkmcnt(0)" ::: "memory");
    __builtin_amdgcn_sched_barrier(0);
    short8 ccA[4];
    #pragma unroll
    for (int kf=0; kf<4; ++kf){
      U8 u; u.v = *(const uvec4*)&sh_tr[scb + ln*136 + kf*32 + quad*8];
      ccA[kf] = u.s;
    }
    __builtin_amdgcn_sched_barrier(0);

    // ================= gates GEMM (96 MFMAs, LDS weights), LSTM, publish
    {
      f32x4 acc4[4];
      #pragma unroll
      for (int nt=0; nt<4; ++nt){ acc4[nt][0]=0.f; acc4[nt][1]=0.f; acc4[nt][2]=0.f; acc4[nt][3]=0.f; }

      #pragma unroll
      for (int kf=0; kf<4; ++kf){                 // c_c
        #pragma unroll
        for (int nt=0; nt<4; ++nt)
          acc4[nt] = mfma16(ccA[kf], frag_of(sh_g[(nt*24+kf)*64+lane]), acc4[nt]);
      }
      #pragma unroll
      for (int kf=0; kf<4; ++kf){                 // m
        #pragma unroll
        for (int nt=0; nt<4; ++nt)
          acc4[nt] = mfma16(mA[kf], frag_of(sh_g[(nt*24+4+kf)*64+lane]), acc4[nt]);
      }
      #pragma unroll
      for (int kf=0; kf<16; ++kf){                // h_dec (VGPR frags)
        #pragma unroll
        for (int nt=0; nt<4; ++nt)
          acc4[nt] = mfma16(hA[kf], frag_of(sh_g[(nt*24+8+kf)*64+lane]), acc4[nt]);
      }

      // gamma_h(t+1) from prefetched deltas(t+1)
      short8 dnx[4];
      #pragma unroll
      for (int kf=0; kf<4; ++kf){
        fvec4 lo = dpre[2*kf], hi = dpre[2*kf+1];
        U8 p8;
        p8.u[0] = (unsigned)f2bf(lo.x) | ((unsigned)f2bf(lo.y)<<16);
        p8.u[1] = (unsigned)f2bf(lo.z) | ((unsigned)f2bf(lo.w)<<16);
        p8.u[2] = (unsigned)f2bf(hi.x) | ((unsigned)f2bf(hi.y)<<16);
        p8.u[3] = (unsigned)f2bf(hi.z) | ((unsigned)f2bf(hi.w)<<16);
        dnx[kf] = p8.s;
      }
      f32x4 ahn; ahn[0]=0.f; ahn[1]=0.f; ahn[2]=0.f; ahn[3]=0.f;
      #pragma unroll
      for (int kf=0; kf<4; ++kf) ahn = mfma16(dnx[kf], frag_of(pB[kf]), ahn);

      #pragma unroll
      for (int i=0;i<4;++i){
        float ig = sigm(acc4[0][i] + gbias[0]);
        float fg = sigm(acc4[1][i] + gbias[1]);
        float gg = tanh_(acc4[2][i] + gbias[2]);
        float og = sigm(acc4[3][i] + gbias[3]);
        cs[i] = fg*cs[i] + ig*gg;
        hs[i] = og*tanh_(cs[i]);
        float ghn = fexp2(-LOG2E * fmaxf(ahn[i]+bias_dh, 0.f));
        scatter_ex(exh_nx, w, 16, quad*4+i, r*16+ln, hs[i]*ghn);
      }
    }
    // single barrier at top of next iteration drains + publishes
  }
}

// ---------------------------------------------------------------------------
// Workspace layout (bytes)
#define OFF_G   0u
#define SZ_G    3145728u              // 32 roles x 4nt x 24kf x 1KB
#define OFF_DH  (OFF_G + SZ_G)
#define SZ_DH   131072u
#define OFF_HR  (OFF_DH + SZ_DH)
#define SZ_HR   131072u
#define OFF_DX  (OFF_HR + SZ_HR)
#define SZ_DX   32768u
#define OFF_FR  (OFF_DX + SZ_DX)
#define SZ_FR   32768u
#define OFF_WC  (OFF_FR + SZ_FR)
#define SZ_WC   65536u
#define OFF_EX  (OFF_WC + SZ_WC)
#define SZ_EX   1048576u              // 2 parity x 8 groups x 64KB (h_dec only)
#define OFF_BAR (OFF_EX + SZ_EX)
#define SZ_BAR  4096u                 // 8 groups x 512B flag-array stride
#define WS_NEED (OFF_BAR + SZ_BAR)

extern "C" void kernel_launch(void* const* d_in, const int* in_sizes, int n_in,
                              void* d_out, int out_size, void* d_ws, size_t ws_size,
                              hipStream_t stream) {
  const float* values = (const float*)d_in[0];
  const int*   masks  = (const int*)  d_in[1];
  const float* deltas = (const float*)d_in[2];
  const float* W_dh = (const float*)d_in[3];  const float* b_dh = (const float*)d_in[4];
  const float* W_dx = (const float*)d_in[5];  const float* b_dx = (const float*)d_in[6];
  const float* W_hr = (const float*)d_in[7];  const float* b_hr = (const float*)d_in[8];
  const float* W_fr = (const float*)d_in[9];  const float* b_fr = (const float*)d_in[10];
  const float* W_wc = (const float*)d_in[11]; const float* b_wc = (const float*)d_in[12];
  const float* W_ih = (const float*)d_in[13]; const float* W_hh = (const float*)d_in[14];
  const float* b_ih = (const float*)d_in[15]; const float* b_hh = (const float*)d_in[16];

  if (ws_size < (size_t)WS_NEED) return;

  char* ws = (char*)d_ws;
  uvec4* BG  = (uvec4*)(ws + OFF_G);
  uvec4* BDH = (uvec4*)(ws + OFF_DH);
  uvec4* BHR = (uvec4*)(ws + OFF_HR);
  uvec4* BDX = (uvec4*)(ws + OFF_DX);
  uvec4* BFR = (uvec4*)(ws + OFF_FR);
  uvec4* BWC = (uvec4*)(ws + OFF_WC);
  unsigned short* EX = (unsigned short*)(ws + OFF_EX);
  unsigned* BAR = (unsigned*)(ws + OFF_BAR);

  pack_gates<<<768, 256, 0, stream>>>(W_ih, W_hh, BG);
  pack_generic<<<32, 256, 0, stream>>>(W_dh, BDH, 4, 128, 32*4*64);
  pack_generic<<<32, 256, 0, stream>>>(W_hr, BHR, 16, 512, 8*16*64);
  pack_generic<<<8, 256, 0, stream>>>(W_dx, BDX, 4, 128, 8*4*64);
  pack_generic<<<8, 256, 0, stream>>>(W_fr, BFR, 4, 128, 8*4*64);
  pack_generic<<<16, 256, 0, stream>>>(W_wc, BWC, 8, 256, 8*8*64);
  hipMemsetAsync(ws + OFF_BAR, 0, SZ_BAR, stream);

  rits_main<<<dim3(256), dim3(256), 0, stream>>>(
    values, masks, deltas,
    b_dh, b_dx, b_hr, b_fr, b_wc, b_ih, b_hh,
    BG, BDH, BHR, BDX, BFR, BWC,
    EX, BAR,
    (float*)d_out);
}

// Round 10
// 2846.393 us; speedup vs baseline: 10.0119x; 10.0119x over previous
//
#include <hip/hip_runtime.h>

// ---------------------------------------------------------------------------
// RITS recurrent scan, model-parallel persistent kernel, v3.3.
// 8 groups x 64 batch rows; group = 32 blocks (1/CU), g = bid>>5, r = bid&31.
// Block (g,r): owns H-slice [16r,16r+16) and F-tile ft = r&7 (rep = r>>3).
// PROVEN protocol (R1/R4/R8): sc1 exchange stores/loads through the LLC,
// sc1 flag-array barrier. 4 waves/block; wave w owns 16 rows end-to-end.
//
// v3.3 vs v3.2 (3951us): barriers split into bar_arrive (drain+flag publish)
// and bar_wait (poll+sync), with barrier-INDEPENDENT work moved into the
// stall windows:
//   B2 window: next-step gamma MFMAs + gamma_x(t+1) publish (was in P2)
//   B3 window: the 80/96 gate MFMAs needing only m + h_dec (hA live in VGPRs);
//              only the 16 c_c MFMAs remain after the wait
//   B1 window: next step's mask/value loads issued at end of P3 (in flight
//              through the wait); filler packs frags from returned regs
// Everything else (layout, parity, seq, publish roles) identical to v3.2.
// Gates (96KB), W_hr[ft] (16KB), W_wc[ft] (8KB) in LDS = 120KB, 1 block/CU.
// ---------------------------------------------------------------------------

using short8 = __attribute__((ext_vector_type(8))) short;
using f32x4  = __attribute__((ext_vector_type(4))) float;
using fvec4  = __attribute__((ext_vector_type(4))) float;
using ivec4  = __attribute__((ext_vector_type(4))) int;
using uvec4  = __attribute__((ext_vector_type(4))) unsigned int;

#define LOG2E 1.4426950408889634f

union U8 {
  unsigned u[4];
  unsigned long long q[2];
  short8 s;
  uvec4 v;
};

static __device__ __forceinline__ unsigned short f2bf(float f){
  unsigned u = __builtin_bit_cast(unsigned, f);
  u += 0x7fffu + ((u>>16)&1u);
  return (unsigned short)(u>>16);
}
static __device__ __forceinline__ float fexp2(float x){ return __builtin_amdgcn_exp2f(x); }
static __device__ __forceinline__ float frcp(float x){ return __builtin_amdgcn_rcpf(x); }
static __device__ __forceinline__ float sigm(float x){ return frcp(1.f + fexp2(-LOG2E*x)); }
static __device__ __forceinline__ float tanh_(float x){
  x = fminf(fmaxf(x,-10.f),10.f);
  float e = fexp2(2.f*LOG2E*x);
  return (e-1.f)*frcp(e+1.f);
}
static __device__ __forceinline__ f32x4 mfma16(short8 a, short8 b, f32x4 c){
  return __builtin_amdgcn_mfma_f32_16x16x32_bf16(a,b,c,0,0,0);
}
static __device__ __forceinline__ short8 frag_of(uvec4 v){ return __builtin_bit_cast(short8, v); }

// 16B frag load from exchange buffer (agent-scope relaxed -> sc1, reads LLC).
static __device__ __forceinline__ short8 ex_frag(const unsigned short* p){
  const unsigned long long* q = (const unsigned long long*)p;
  U8 u;
  u.q[0] = __hip_atomic_load(q,     __ATOMIC_RELAXED, __HIP_MEMORY_SCOPE_AGENT);
  u.q[1] = __hip_atomic_load(q + 1, __ATOMIC_RELAXED, __HIP_MEMORY_SCOPE_AGENT);
  return u.s;
}

// u16 store with agent-scope coherence (write-through to LLC). PROVEN.
static __device__ __forceinline__ void st16_sc1(unsigned short* p, unsigned short v){
  unsigned vv = v;
  asm volatile("global_store_short %0, %1, off sc1" :: "v"(p), "v"(vv) : "memory");
}

// scatter one bf16 value at (row-in-tile rl, k-dim kk) into a 16x16x32
// A-frag-major exchange region with KF k-frags, m-tile mt. (proven layout)
static __device__ __forceinline__ void scatter_ex(unsigned short* exbuf, int mt, int KF,
                                                  int rl, int kk, float val){
  int kf = kk>>5, ko = kk&31;
  int L = rl + 16*(ko>>3);
  long off = ((long)(mt*KF+kf)*64 + L)*8 + (ko&7);
  st16_sc1(exbuf + off, f2bf(val));
}

// mask A-frag from two ivec4 register values (mask values exactly 0/1).
static __device__ __forceinline__ short8 mi_frag(ivec4 a, ivec4 b){
  U8 t;
  t.u[0] = (a.x?0x3F80u:0u) | ((a.y?0x3F80u:0u)<<16);
  t.u[1] = (a.z?0x3F80u:0u) | ((a.w?0x3F80u:0u)<<16);
  t.u[2] = (b.x?0x3F80u:0u) | ((b.y?0x3F80u:0u)<<16);
  t.u[3] = (b.z?0x3F80u:0u) | ((b.w?0x3F80u:0u)<<16);
  return t.s;
}

// Barrier split (same protocol as proven group_barrier, R2/R4/R8).
// bar_arrive: per-wave vmcnt(0) drains all sc1 stores to the LLC; after
// __syncthreads the block's data is LLC-visible; thread0 publishes seq.
// bar_wait: wave0 polls all 32 flags (one 32-lane sc1 load + __all), then
// __syncthreads releases the block. Barrier-independent work goes between.
static __device__ __forceinline__ void bar_arrive(unsigned* flags, int r, unsigned seq){
  asm volatile("s_waitcnt vmcnt(0)" ::: "memory");
  __syncthreads();
  if (threadIdx.x == 0)
    __hip_atomic_store(flags + r, seq, __ATOMIC_RELAXED, __HIP_MEMORY_SCOPE_AGENT);
}
static __device__ __forceinline__ void bar_wait(unsigned* flags, int w, int lane, unsigned seq){
  if (w == 0){
    for (;;){
      unsigned v = __hip_atomic_load(flags + (lane & 31), __ATOMIC_RELAXED,
                                     __HIP_MEMORY_SCOPE_AGENT);
      if (__all(v >= seq)) break;
      __builtin_amdgcn_s_sleep(1);
    }
  }
  __syncthreads();
}

// ---------------------------------------------------------------------------
// Weight packing. B-frag: frag (tile,kf) holds B[n=tile*16+(lane&15)]
// [k=kf*32+(lane>>4)*8+j], 16B/lane.
// ---------------------------------------------------------------------------
__global__ void pack_generic(const float* __restrict__ src, uvec4* __restrict__ dst,
                             int KF, int srcK, int total){
  int t = blockIdx.x*256 + threadIdx.x;
  if (t >= total) return;
  int lane = t & 63, frag = t >> 6;
  int kf = frag % KF, tile = frag / KF;
  int n  = tile*16 + (lane & 15);
  int k0 = kf*32 + ((lane>>4)<<3);
  const float* s = src + (long)n*srcK + k0;
  U8 o;
  o.u[0] = (unsigned)f2bf(s[0]) | ((unsigned)f2bf(s[1])<<16);
  o.u[1] = (unsigned)f2bf(s[2]) | ((unsigned)f2bf(s[3])<<16);
  o.u[2] = (unsigned)f2bf(s[4]) | ((unsigned)f2bf(s[5])<<16);
  o.u[3] = (unsigned)f2bf(s[6]) | ((unsigned)f2bf(s[7])<<16);
  dst[t] = o.v;
}

// Gates blob: per role r, 4 n-tiles x 24 k-frags; n-tile = GATE, col = h_local
// (R = nt*512 + r*16 + n). K order: [c_c 0..127, m 128..255, h_dec 0..511].
__global__ void pack_gates(const float* __restrict__ Wih, const float* __restrict__ Whh,
                           uvec4* __restrict__ dst){
  int t = blockIdx.x*256 + threadIdx.x;
  if (t >= 3072*64) return;
  int lane = t & 63, frag = t >> 6;
  int kf = frag % 24; int rnt = frag / 24;
  int nt = rnt & 3; int r = rnt >> 2;
  int Rrow = nt*512 + r*16 + (lane & 15);
  int k = kf*32 + ((lane>>4)<<3);
  const float* s = (kf < 8) ? (Wih + (long)Rrow*256 + k)
                            : (Whh + (long)Rrow*512 + (k - 256));
  U8 o;
  o.u[0] = (unsigned)f2bf(s[0]) | ((unsigned)f2bf(s[1])<<16);
  o.u[1] = (unsigned)f2bf(s[2]) | ((unsigned)f2bf(s[3])<<16);
  o.u[2] = (unsigned)f2bf(s[4]) | ((unsigned)f2bf(s[5])<<16);
  o.u[3] = (unsigned)f2bf(s[6]) | ((unsigned)f2bf(s[7])<<16);
  dst[t] = o.v;
}

// ---------------------------------------------------------------------------
__global__ __launch_bounds__(256,1) void rits_main(
  const float* __restrict__ values, const int* __restrict__ masks, const float* __restrict__ deltas,
  const float* __restrict__ b_dh, const float* __restrict__ b_dx, const float* __restrict__ b_hr,
  const float* __restrict__ b_fr, const float* __restrict__ b_wc,
  const float* __restrict__ b_ih, const float* __restrict__ b_hh,
  const uvec4* __restrict__ BG, const uvec4* __restrict__ BDH, const uvec4* __restrict__ BHR,
  const uvec4* __restrict__ BDX, const uvec4* __restrict__ BFR, const uvec4* __restrict__ BWC,
  unsigned short* __restrict__ EX, unsigned* __restrict__ BAR,
  float* __restrict__ out)
{
  __shared__ __align__(16) uvec4 sh_g[96*64];        // 96KB gates B-frags
  __shared__ __align__(16) uvec4 sh_whr[16*64];      // 16KB W_hr tile frags
  __shared__ __align__(16) uvec4 sh_wwc[8*64];       //  8KB W_wc tile frags
                                                     // 120KB, 1 block/CU

  const int tid = threadIdx.x;
  const int w = tid>>6, lane = tid&63, quad = lane>>4, ln = lane&15;
  const int g = blockIdx.x >> 5, r = blockIdx.x & 31, ft = r & 7, rep = r >> 3;

  for (int idx = tid; idx < 96*64; idx += 256) sh_g[idx]   = BG[(long)r*6144 + idx];
  for (int idx = tid; idx < 16*64; idx += 256) sh_whr[idx] = BHR[ft*1024 + idx];
  for (int idx = tid; idx < 8*64;  idx += 256) sh_wwc[idx] = BWC[ft*512 + idx];

  uvec4 pB[8];                                   // dh kf0..3, dx kf0..3
  #pragma unroll
  for (int kf=0; kf<4; ++kf){
    pB[kf]   = BDH[(r*4+kf)*64+lane];
    pB[4+kf] = BDX[(ft*4+kf)*64+lane];
  }
  uvec4 fB[4];
  #pragma unroll
  for (int kf=0; kf<4; ++kf) fB[kf] = BFR[(ft*4+kf)*64+lane];

  const float bias_dh = b_dh[r*16+ln];
  const float bias_dx = b_dx[ft*16+ln];
  const float bias_hr = b_hr[ft*16+ln];
  const float bias_fr = b_fr[ft*16+ln];
  const float bias_wc = b_wc[ft*16+ln];
  float gbias[4];
  #pragma unroll
  for (int nt=0; nt<4; ++nt){
    int Rr = nt*512 + r*16 + ln;
    gbias[nt] = b_ih[Rr] + b_hh[Rr];
  }

  float hs[4] = {0,0,0,0}, cs[4] = {0,0,0,0};

  unsigned* flags = BAR + g*128;                           // 512B group stride
  unsigned seq = 0;

  unsigned short* const exb0 = EX + (long)g*57344;          // parity 0
  unsigned short* const exb1 = EX + (long)(8+g)*57344;      // parity 1

  const long rowA = (long)(g*64 + w*16 + ln);               // A-frag row (m=ln)

  // ---- prologue: deltas(0) + masks/values(0) prefetch; publish h_dec(0)=0
  //      and gamma_x(0) (rep1); arrive B1.
  fvec4 dpre[8];
  ivec4 maA[4], maB[4];
  int   mmn[4]; float vvn[4]; long ionx[4];
  {
    const long ib0 = rowA*256*128;
    #pragma unroll
    for (int kf=0; kf<4; ++kf){
      int c0 = kf*32 + quad*8;
      dpre[2*kf]   = *(const fvec4*)(deltas + ib0 + c0);
      dpre[2*kf+1] = *(const fvec4*)(deltas + ib0 + c0 + 4);
      maA[kf] = *(const ivec4*)(masks + ib0 + c0);
      maB[kf] = *(const ivec4*)(masks + ib0 + c0 + 4);
    }
    #pragma unroll
    for (int i=0;i<4;++i){
      ionx[i] = ((long)(g*64 + w*16 + quad*4 + i)*256 + 0)*128 + ft*16 + ln;
      mmn[i] = masks[ionx[i]];
      vvn[i] = values[ionx[i]];
    }
  }
  __syncthreads();                                 // LDS weights ready
  {
    #pragma unroll
    for (int i=0;i<4;++i)
      scatter_ex(exb0, w, 16, quad*4+i, r*16+ln, 0.f);
    if (rep == 1){
      short8 d0[4];
      #pragma unroll
      for (int kf=0; kf<4; ++kf){
        fvec4 lo = dpre[2*kf], hi = dpre[2*kf+1];
        U8 p8;
        p8.u[0] = (unsigned)f2bf(lo.x) | ((unsigned)f2bf(lo.y)<<16);
        p8.u[1] = (unsigned)f2bf(lo.z) | ((unsigned)f2bf(lo.w)<<16);
        p8.u[2] = (unsigned)f2bf(hi.x) | ((unsigned)f2bf(hi.y)<<16);
        p8.u[3] = (unsigned)f2bf(hi.z) | ((unsigned)f2bf(hi.w)<<16);
        d0[kf] = p8.s;
      }
      f32x4 ax = {0.f,0.f,0.f,0.f};
      #pragma unroll
      for (int kf=0; kf<4; ++kf) ax = mfma16(d0[kf], frag_of(pB[4+kf]), ax);
      #pragma unroll
      for (int i=0;i<4;++i){
        float gx = fexp2(-LOG2E * fmaxf(ax[i]+bias_dx, 0.f));
        scatter_ex(exb0 + 40960, w, 4, quad*4+i, ft*16+ln, gx);
      }
    }
  }
  bar_arrive(flags, r, ++seq);                     // B1(t=0)

  for (int t=0; t<256; ++t){
    unsigned short* const exh    = (t & 1) ? exb1 : exb0;
    unsigned short* const exh_nx = (t & 1) ? exb0 : exb1;
    unsigned short* const exxc = exh + 32768;
    unsigned short* const exgx = exh + 40960;
    unsigned short* const excc = exh + 49152;
    unsigned short* const exgx_nx = exh_nx + 40960;

    // ===== B1 window filler: pack mA from prefetched regs; commit mm/vv/io
    short8 mA[4];
    #pragma unroll
    for (int kf=0; kf<4; ++kf) mA[kf] = mi_frag(maA[kf], maB[kf]);
    int mm[4]; float vv[4]; long io[4];
    #pragma unroll
    for (int i=0;i<4;++i){ mm[i]=mmn[i]; vv[i]=vvn[i]; io[i]=ionx[i]; }
    bar_wait(flags, w, lane, seq);                 // B1: h_dec(t) visible

    // ================= P1: x_h (K=512, one wave), x_c publish (rep2)
    short8 hA[16];                                 // live until P3
    #pragma unroll
    for (int kf=0; kf<16; ++kf)
      hA[kf] = ex_frag(exh + ((long)(w*16+kf)*64 + lane)*8);
    {  // issue deltas(t+1) prefetch behind the critical hA loads
      const long ibn = (rowA*256 + ((t+1)&255))*128;
      #pragma unroll
      for (int kf=0; kf<4; ++kf){
        int c0 = kf*32 + quad*8;
        dpre[2*kf]   = *(const fvec4*)(deltas + ibn + c0);
        dpre[2*kf+1] = *(const fvec4*)(deltas + ibn + c0 + 4);
      }
    }
    float xh_r[4];
    {
      f32x4 x0 = {0.f,0.f,0.f,0.f}, x1 = {0.f,0.f,0.f,0.f};
      #pragma unroll
      for (int kf=0; kf<8; ++kf){
        x0 = mfma16(hA[kf],   frag_of(sh_whr[kf*64+lane]),     x0);
        x1 = mfma16(hA[8+kf], frag_of(sh_whr[(8+kf)*64+lane]), x1);
      }
      #pragma unroll
      for (int i=0;i<4;++i){
        float xh = x0[i] + x1[i] + bias_hr;
        xh_r[i] = xh;
        if (rep == 2){
          float xc = mm[i] ? vv[i] : xh;
          scatter_ex(exxc, w, 4, quad*4+i, ft*16+ln, xc);
        }
      }
    }
    bar_arrive(flags, r, ++seq);                   // B2 arrive

    // ===== B2 window filler: next-step gammas (dpre(t+1) drained by arrive)
    float ghn[4];
    {
      short8 dnx[4];
      #pragma unroll
      for (int kf=0; kf<4; ++kf){
        fvec4 lo = dpre[2*kf], hi = dpre[2*kf+1];
        U8 p8;
        p8.u[0] = (unsigned)f2bf(lo.x) | ((unsigned)f2bf(lo.y)<<16);
        p8.u[1] = (unsigned)f2bf(lo.z) | ((unsigned)f2bf(lo.w)<<16);
        p8.u[2] = (unsigned)f2bf(hi.x) | ((unsigned)f2bf(hi.y)<<16);
        p8.u[3] = (unsigned)f2bf(hi.z) | ((unsigned)f2bf(hi.w)<<16);
        dnx[kf] = p8.s;
      }
      f32x4 ahn = {0.f,0.f,0.f,0.f};
      #pragma unroll
      for (int kf=0; kf<4; ++kf) ahn = mfma16(dnx[kf], frag_of(pB[kf]), ahn);
      #pragma unroll
      for (int i=0;i<4;++i)
        ghn[i] = fexp2(-LOG2E * fmaxf(ahn[i]+bias_dh, 0.f));
      if (rep == 1){
        f32x4 axn = {0.f,0.f,0.f,0.f};
        #pragma unroll
        for (int kf=0; kf<4; ++kf) axn = mfma16(dnx[kf], frag_of(pB[4+kf]), axn);
        #pragma unroll
        for (int i=0;i<4;++i){
          float gx = fexp2(-LOG2E * fmaxf(axn[i]+bias_dx, 0.f));
          scatter_ex(exgx_nx, w, 4, quad*4+i, ft*16+ln, gx);
        }
      }
    }
    bar_wait(flags, w, lane, seq);                 // B2: x_c, gamma_x visible

    // ================= P2: z_h & alpha, c_c + out publish (rep3)
    {
      f32x4 az = {0.f,0.f,0.f,0.f};
      #pragma unroll
      for (int kf=0; kf<4; ++kf){
        short8 a = ex_frag(exxc + ((long)(w*4+kf)*64 + lane)*8);
        az = mfma16(a, frag_of(fB[kf]), az);
      }
      f32x4 aa = {0.f,0.f,0.f,0.f};
      #pragma unroll
      for (int kf=0; kf<4; ++kf){
        short8 a = ex_frag(exgx + ((long)(w*4+kf)*64 + lane)*8);
        aa = mfma16(a, frag_of(sh_wwc[kf*64+lane]), aa);
      }
      #pragma unroll
      for (int kf=0; kf<4; ++kf)
        aa = mfma16(mA[kf], frag_of(sh_wwc[(4+kf)*64+lane]), aa);
      #pragma unroll
      for (int i=0;i<4;++i){
        float zh = az[i] + bias_fr;
        float al = aa[i] + bias_wc;
        float ch = al*zh + (1.f-al)*xh_r[i];
        float cc = mm[i] ? vv[i] : ch;
        if (rep == 3){
          out[io[i]] = cc;
          scatter_ex(excc, w, 4, quad*4+i, ft*16+ln, cc);
        }
      }
    }
    bar_arrive(flags, r, ++seq);                   // B3 arrive

    // ===== B3 window filler: gates m-part + h_dec-part (80 of 96 MFMAs)
    f32x4 acc4[4];
    #pragma unroll
    for (int nt=0; nt<4; ++nt){ acc4[nt][0]=0.f; acc4[nt][1]=0.f; acc4[nt][2]=0.f; acc4[nt][3]=0.f; }
    #pragma unroll
    for (int kf=0; kf<4; ++kf){                    // m
      #pragma unroll
      for (int nt=0; nt<4; ++nt)
        acc4[nt] = mfma16(mA[kf], frag_of(sh_g[(nt*24+4+kf)*64+lane]), acc4[nt]);
    }
    #pragma unroll
    for (int kf=0; kf<16; ++kf){                   // h_dec (VGPR frags)
      #pragma unroll
      for (int nt=0; nt<4; ++nt)
        acc4[nt] = mfma16(hA[kf], frag_of(sh_g[(nt*24+8+kf)*64+lane]), acc4[nt]);
    }
    bar_wait(flags, w, lane, seq);                 // B3: c_c visible

    // ================= P3: gates c_c-part, LSTM update, publish h_dec(t+1)
    {
      #pragma unroll
      for (int kf=0; kf<4; ++kf){                  // c_c
        short8 a = ex_frag(excc + ((long)(w*4+kf)*64 + lane)*8);
        #pragma unroll
        for (int nt=0; nt<4; ++nt)
          acc4[nt] = mfma16(a, frag_of(sh_g[(nt*24+kf)*64+lane]), acc4[nt]);
      }
      #pragma unroll
      for (int i=0;i<4;++i){
        float ig = sigm(acc4[0][i] + gbias[0]);
        float fg = sigm(acc4[1][i] + gbias[1]);
        float gg = tanh_(acc4[2][i] + gbias[2]);
        float og = sigm(acc4[3][i] + gbias[3]);
        cs[i] = fg*cs[i] + ig*gg;
        hs[i] = og*tanh_(cs[i]);
        scatter_ex(exh_nx, w, 16, quad*4+i, r*16+ln, hs[i]*ghn[i]);
      }
    }
    bar_arrive(flags, r, ++seq);                   // B1 of t+1

    // ===== issue next step's mask/value prefetch (in flight through B1 wait)
    {
      const int tn = (t+1)&255;
      const long ibn = (rowA*256 + tn)*128;
      #pragma unroll
      for (int kf=0; kf<4; ++kf){
        int c0 = kf*32 + quad*8;
        maA[kf] = *(const ivec4*)(masks + ibn + c0);
        maB[kf] = *(const ivec4*)(masks + ibn + c0 + 4);
      }
      #pragma unroll
      for (int i=0;i<4;++i){
        ionx[i] = ((long)(g*64 + w*16 + quad*4 + i)*256 + tn)*128 + ft*16 + ln;
        mmn[i] = masks[ionx[i]];
        vvn[i] = values[ionx[i]];
      }
    }
  }
}

// ---------------------------------------------------------------------------
// Workspace layout (bytes)
#define OFF_G   0u
#define SZ_G    3145728u              // 32 roles x 4nt x 24kf x 1KB
#define OFF_DH  (OFF_G + SZ_G)
#define SZ_DH   131072u
#define OFF_HR  (OFF_DH + SZ_DH)
#define SZ_HR   131072u
#define OFF_DX  (OFF_HR + SZ_HR)
#define SZ_DX   32768u
#define OFF_FR  (OFF_DX + SZ_DX)
#define SZ_FR   32768u
#define OFF_WC  (OFF_FR + SZ_FR)
#define SZ_WC   65536u
#define OFF_EX  (OFF_WC + SZ_WC)
#define SZ_EX   1835008u              // 2 parity x 8 groups x 112KB
#define OFF_BAR (OFF_EX + SZ_EX)
#define SZ_BAR  4096u                 // 8 groups x 512B flag-array stride
#define WS_NEED (OFF_BAR + SZ_BAR)

extern "C" void kernel_launch(void* const* d_in, const int* in_sizes, int n_in,
                              void* d_out, int out_size, void* d_ws, size_t ws_size,
                              hipStream_t stream) {
  const float* values = (const float*)d_in[0];
  const int*   masks  = (const int*)  d_in[1];
  const float* deltas = (const float*)d_in[2];
  const float* W_dh = (const float*)d_in[3];  const float* b_dh = (const float*)d_in[4];
  const float* W_dx = (const float*)d_in[5];  const float* b_dx = (const float*)d_in[6];
  const float* W_hr = (const float*)d_in[7];  const float* b_hr = (const float*)d_in[8];
  const float* W_fr = (const float*)d_in[9];  const float* b_fr = (const float*)d_in[10];
  const float* W_wc = (const float*)d_in[11]; const float* b_wc = (const float*)d_in[12];
  const float* W_ih = (const float*)d_in[13]; const float* W_hh = (const float*)d_in[14];
  const float* b_ih = (const float*)d_in[15]; const float* b_hh = (const float*)d_in[16];

  if (ws_size < (size_t)WS_NEED) return;

  char* ws = (char*)d_ws;
  uvec4* BG  = (uvec4*)(ws + OFF_G);
  uvec4* BDH = (uvec4*)(ws + OFF_DH);
  uvec4* BHR = (uvec4*)(ws + OFF_HR);
  uvec4* BDX = (uvec4*)(ws + OFF_DX);
  uvec4* BFR = (uvec4*)(ws + OFF_FR);
  uvec4* BWC = (uvec4*)(ws + OFF_WC);
  unsigned short* EX = (unsigned short*)(ws + OFF_EX);
  unsigned* BAR = (unsigned*)(ws + OFF_BAR);

  pack_gates<<<768, 256, 0, stream>>>(W_ih, W_hh, BG);
  pack_generic<<<32, 256, 0, stream>>>(W_dh, BDH, 4, 128, 32*4*64);
  pack_generic<<<32, 256, 0, stream>>>(W_hr, BHR, 16, 512, 8*16*64);
  pack_generic<<<8, 256, 0, stream>>>(W_dx, BDX, 4, 128, 8*4*64);
  pack_generic<<<8, 256, 0, stream>>>(W_fr, BFR, 4, 128, 8*4*64);
  pack_generic<<<16, 256, 0, stream>>>(W_wc, BWC, 8, 256, 8*8*64);
  hipMemsetAsync(ws + OFF_BAR, 0, SZ_BAR, stream);

  rits_main<<<dim3(256), dim3(256), 0, stream>>>(
    values, masks, deltas,
    b_dh, b_dx, b_hr, b_fr, b_wc, b_ih, b_hh,
    BG, BDH, BHR, BDX, BFR, BWC,
    EX, BAR,
    (float*)d_out);
}